// Round 1
// baseline (236421.826 us; speedup 1.0000x reference)
//
#include <hip/hip_runtime.h>
#include <math.h>

#define DZ 128
#define DX 64
#define KMIX 16
#define JITTER_C 1e-4f

// =====================================================================
// mm_core: acc[a][b] += sum_k At[k][i0+a] * B[k][j0+b]
// i.e. C = A*B where At holds A transposed (row k = column k of A).
// Works for LDS or global pointers. TM,TN in {4,8}.
// =====================================================================
template<int TM, int TN, int K>
__device__ __forceinline__ void mm_core(const float* __restrict__ At, int lda,
                                        const float* __restrict__ B, int ldb,
                                        int i0, int j0, float* __restrict__ acc)
{
#pragma unroll 2
    for (int k = 0; k < K; ++k) {
        const float* ar = At + k * lda + i0;
        const float* br = B + k * ldb + j0;
        float av[TM], bv[TN];
#pragma unroll
        for (int a = 0; a < TM; a += 4) {
            float4 t = *reinterpret_cast<const float4*>(ar + a);
            av[a] = t.x; av[a + 1] = t.y; av[a + 2] = t.z; av[a + 3] = t.w;
        }
#pragma unroll
        for (int b = 0; b < TN; b += 4) {
            float4 t = *reinterpret_cast<const float4*>(br + b);
            bv[b] = t.x; bv[b + 1] = t.y; bv[b + 2] = t.z; bv[b + 3] = t.w;
        }
#pragma unroll
        for (int a = 0; a < TM; ++a)
#pragma unroll
            for (int b = 0; b < TN; ++b)
                acc[a * TN + b] = fmaf(av[a], bv[b], acc[a * TN + b]);
    }
}

// =====================================================================
// prep: Ct[z][m] = C[m][z]   (C^T, 128x64)
// =====================================================================
__global__ void kf_prep(const float* __restrict__ Cm, float* __restrict__ Ct)
{
    for (int i = threadIdx.x; i < DZ * DX; i += 256) {
        int z = i >> 6, m = i & 63;
        Ct[i] = Cm[m * DZ + z];
    }
}

// =====================================================================
// phase 1: per step k (one block per step) compute
//   G  = F^T            (F = R(h*eA), RK stability polynomial, deg 6)
//   Qe = h * sum_{m=0..5} gamma[m+1] * (hL)^m [eQ]   (exact RK noise term)
//   c  = h * sum_{m=0..5} gamma[m+1] * (h*eA)^m eb   (exact RK bias term)
// =====================================================================
__global__ __launch_bounds__(256) void kf_phase1(
    const float* __restrict__ A_s, const float* __restrict__ b_s,
    const float* __restrict__ Qch, const float* __restrict__ es,
    const float* __restrict__ ts,
    float* __restrict__ Gb, float* __restrict__ Qb, float* __restrict__ cb,
    int pred_start,
    float g1, float g2, float g3, float g4, float g5, float g6)
{
    __shared__ float hAt[DZ * DZ];   // (h*eA)^T
    __shared__ float Xs[DZ * DZ];    // working matrix (row-major)
    __shared__ float wsh[KMIX];
    __shared__ float ebv[DZ];
    __shared__ float eqv[DZ];
    __shared__ float vv[DZ];

    const int tid = threadIdx.x;
    const int tx = tid & 15, ty = tid >> 4;
    const int i0 = ty * 8, j0 = tx * 8;
    const int k = pred_start + blockIdx.x;
    float* Gk = Gb + (size_t)blockIdx.x * (DZ * DZ);
    float* Qk = Qb + (size_t)blockIdx.x * (DZ * DZ);
    float* ck = cb + (size_t)blockIdx.x * DZ;
    const float h = ts[k] - ts[k - 1];
    float g[7];
    g[0] = 1.f; g[1] = g1; g[2] = g2; g[3] = g3; g[4] = g4; g[5] = g5; g[6] = g6;

    if (h <= 0.f) {   // reference: no integration -> identity map
        for (int i = tid; i < DZ * DZ; i += 256) {
            int r = i >> 7, c = i & 127;
            Gk[i] = (r == c) ? 1.f : 0.f;
            Qk[i] = 0.f;
        }
        if (tid < DZ) ck[tid] = 0.f;
        return;
    }

    // weights
    if (tid < KMIX) wsh[tid] = es[(size_t)k * KMIX + tid];
    __syncthreads();
    if (tid == 0) {
        float s = 0.f;
        for (int m = 0; m < KMIX; ++m) s += wsh[m];
        float inv = 1.f / s;
        for (int m = 0; m < KMIX; ++m) wsh[m] *= inv;
    }
    __syncthreads();

    if (tid < DZ) {
        float eb = 0.f, eq = 0.f;
        for (int m = 0; m < KMIX; ++m) {
            float wm = wsh[m];
            eb += wm * b_s[m * DZ + tid];
            float qc = Qch[m * DZ + tid];
            eq += wm * qc * qc;
        }
        ebv[tid] = eb; eqv[tid] = eq;
    }

    // hA tile (h * sum_m w_m A_s[m]) into regs; write hAt (transposed) + Xs (= hA)
    float t64[64];
#pragma unroll
    for (int e = 0; e < 64; ++e) t64[e] = 0.f;
    for (int m = 0; m < KMIX; ++m) {
        float wm = wsh[m];
        const float* Am = A_s + (size_t)m * (DZ * DZ);
#pragma unroll
        for (int a = 0; a < 8; ++a) {
            float4 p0 = *reinterpret_cast<const float4*>(&Am[(i0 + a) * DZ + j0]);
            float4 p1 = *reinterpret_cast<const float4*>(&Am[(i0 + a) * DZ + j0 + 4]);
            t64[a * 8 + 0] = fmaf(wm, p0.x, t64[a * 8 + 0]);
            t64[a * 8 + 1] = fmaf(wm, p0.y, t64[a * 8 + 1]);
            t64[a * 8 + 2] = fmaf(wm, p0.z, t64[a * 8 + 2]);
            t64[a * 8 + 3] = fmaf(wm, p0.w, t64[a * 8 + 3]);
            t64[a * 8 + 4] = fmaf(wm, p1.x, t64[a * 8 + 4]);
            t64[a * 8 + 5] = fmaf(wm, p1.y, t64[a * 8 + 5]);
            t64[a * 8 + 6] = fmaf(wm, p1.z, t64[a * 8 + 6]);
            t64[a * 8 + 7] = fmaf(wm, p1.w, t64[a * 8 + 7]);
        }
    }
#pragma unroll
    for (int a = 0; a < 8; ++a)
#pragma unroll
        for (int b = 0; b < 8; ++b) {
            float v = h * t64[a * 8 + b];
            t64[a * 8 + b] = v;
            Xs[(i0 + a) * DZ + (j0 + b)] = v;
            hAt[(j0 + b) * DZ + (i0 + a)] = v;
        }
    __syncthreads();

    // ---- F = sum_m g[m] (hA)^m ----
    float Fa[64];
#pragma unroll
    for (int a = 0; a < 8; ++a)
#pragma unroll
        for (int b = 0; b < 8; ++b)
            Fa[a * 8 + b] = (((i0 + a) == (j0 + b)) ? 1.f : 0.f) + g[1] * t64[a * 8 + b];

    for (int m = 2; m <= 6; ++m) {
        float xn[64];
#pragma unroll
        for (int e = 0; e < 64; ++e) xn[e] = 0.f;
        mm_core<8, 8, DZ>(hAt, DZ, Xs, DZ, i0, j0, xn);   // xn = hA * X
#pragma unroll
        for (int e = 0; e < 64; ++e) Fa[e] = fmaf(g[m], xn[e], Fa[e]);
        __syncthreads();
#pragma unroll
        for (int a = 0; a < 8; ++a)
#pragma unroll
            for (int b = 0; b < 8; ++b)
                Xs[(i0 + a) * DZ + (j0 + b)] = xn[a * 8 + b];
        __syncthreads();
    }
    // F -> Xs, then store G = F^T coalesced
#pragma unroll
    for (int a = 0; a < 8; ++a)
#pragma unroll
        for (int b = 0; b < 8; ++b)
            Xs[(i0 + a) * DZ + (j0 + b)] = Fa[a * 8 + b];
    __syncthreads();
    if (tid < DZ) {
        for (int i = 0; i < DZ; i += 4) {
            float4 v;
            v.x = Xs[(i + 0) * DZ + tid];
            v.y = Xs[(i + 1) * DZ + tid];
            v.z = Xs[(i + 2) * DZ + tid];
            v.w = Xs[(i + 3) * DZ + tid];
            *reinterpret_cast<float4*>(&Gk[tid * DZ + i]) = v;
        }
    }
    __syncthreads();

    // ---- Q_eff = h * sum_{m=0..5} g[m+1] * Y_m,  Y_0 = eQ, Y_m = hA Y + Y hA^T ----
    float Qa[64];
#pragma unroll
    for (int a = 0; a < 8; ++a)
#pragma unroll
        for (int b = 0; b < 8; ++b) {
            float y0 = ((i0 + a) == (j0 + b)) ? eqv[i0 + a] : 0.f;
            Xs[(i0 + a) * DZ + (j0 + b)] = y0;
            Qa[a * 8 + b] = g[1] * y0;
        }
    __syncthreads();
    for (int m = 1; m <= 5; ++m) {
        float M[64];
#pragma unroll
        for (int e = 0; e < 64; ++e) M[e] = 0.f;
        mm_core<8, 8, DZ>(hAt, DZ, Xs, DZ, i0, j0, M);    // M = hA * Y
        __syncthreads();
#pragma unroll
        for (int a = 0; a < 8; ++a)
#pragma unroll
            for (int b = 0; b < 8; ++b)
                Xs[(i0 + a) * DZ + (j0 + b)] = M[a * 8 + b];
        __syncthreads();
        // Y_next = M + M^T
#pragma unroll
        for (int a = 0; a < 8; ++a)
#pragma unroll
            for (int b = 0; b < 8; ++b)
                M[a * 8 + b] += Xs[(j0 + b) * DZ + (i0 + a)];
#pragma unroll
        for (int e = 0; e < 64; ++e) Qa[e] = fmaf(g[m + 1], M[e], Qa[e]);
        __syncthreads();
#pragma unroll
        for (int a = 0; a < 8; ++a)
#pragma unroll
            for (int b = 0; b < 8; ++b)
                Xs[(i0 + a) * DZ + (j0 + b)] = M[a * 8 + b];
        __syncthreads();
    }
#pragma unroll
    for (int a = 0; a < 8; ++a) {
        float4 v0 = make_float4(h * Qa[a * 8 + 0], h * Qa[a * 8 + 1], h * Qa[a * 8 + 2], h * Qa[a * 8 + 3]);
        float4 v1 = make_float4(h * Qa[a * 8 + 4], h * Qa[a * 8 + 5], h * Qa[a * 8 + 6], h * Qa[a * 8 + 7]);
        *reinterpret_cast<float4*>(&Qk[(i0 + a) * DZ + j0]) = v0;
        *reinterpret_cast<float4*>(&Qk[(i0 + a) * DZ + j0 + 4]) = v1;
    }

    // ---- c = h * sum_{m=0..5} g[m+1] (hA)^m eb ----
    if (tid < DZ) vv[tid] = ebv[tid];
    float creg = (tid < DZ) ? g[1] * ebv[tid] : 0.f;
    __syncthreads();
    for (int m = 1; m <= 5; ++m) {
        float vn = 0.f;
        if (tid < DZ) {
            for (int kk = 0; kk < DZ; ++kk)
                vn = fmaf(hAt[kk * DZ + tid], vv[kk], vn);
        }
        __syncthreads();
        if (tid < DZ) vv[tid] = vn;
        creg = fmaf(g[m + 1], vn, creg);
        __syncthreads();
    }
    if (tid < DZ) ck[tid] = h * creg;
}

// =====================================================================
// phase 2: sequential filter, one block of 256 threads.
// state layout (floats): P[16384], mu[128], Sinv[4096]
// =====================================================================
__global__ __launch_bounds__(256) void kf_phase2(
    const float* __restrict__ xs, const float* __restrict__ Gb,
    const float* __restrict__ Qb, const float* __restrict__ cb,
    const float* __restrict__ Ct, const float* __restrict__ Cm,
    const float* __restrict__ Rm, const float* __restrict__ mu0,
    const float* __restrict__ P0,
    float* __restrict__ mu_out, float* __restrict__ P_out,
    float* __restrict__ state,
    int k0, int k1, int pred_start)
{
    __shared__ float Pl[DZ * DZ];      // P (then P_pr, then P_u)
    __shared__ float Ub[DZ * DZ];      // U / {CPt,CP} / {S,T} / Kgt
    __shared__ float Xinv[DX * DX];    // running S^{-1} (Newton-Schulz)
    __shared__ float muv[DZ];
    __shared__ float mupr[DZ];
    __shared__ float yv[DX];
    __shared__ float rowsum[DX];
    __shared__ float red[1];

    const int tid = threadIdx.x;
    const int tx = tid & 15, ty = tid >> 4;
    const int i08 = ty * 8, j08 = tx * 8;
    const int i04 = ty * 4, j04 = tx * 4;

    if (k0 == 0) {
        for (int i = tid; i < DZ * DZ; i += 256) Pl[i] = P0[i];
        if (tid < DZ) muv[tid] = mu0[tid];
        for (int i = tid; i < DX * DX; i += 256) Xinv[i] = 0.f;
    } else {
        for (int i = tid; i < DZ * DZ; i += 256) Pl[i] = state[i];
        if (tid < DZ) muv[tid] = state[16384 + tid];
        for (int i = tid; i < DX * DX; i += 256) Xinv[i] = state[16512 + i];
    }
    __syncthreads();

    for (int k = k0; k < k1; ++k) {
        if (k > 0) {
            const size_t slot = (size_t)(k - pred_start);
            const float* Gk = Gb + slot * (DZ * DZ);
            const float* Qk = Qb + slot * (DZ * DZ);
            const float* ck = cb + slot * DZ;
            // U = P * F^T   (At = P symmetric, B = G)
            float acc[64];
#pragma unroll
            for (int e = 0; e < 64; ++e) acc[e] = 0.f;
            mm_core<8, 8, DZ>(Pl, DZ, Gk, DZ, i08, j08, acc);
#pragma unroll
            for (int a = 0; a < 8; ++a)
#pragma unroll
                for (int b = 0; b < 8; ++b)
                    Ub[(i08 + a) * DZ + (j08 + b)] = acc[a * 8 + b];
            // mu_pr = F mu + c
            if (tid < DZ) {
                float s = ck[tid];
                for (int kk = 0; kk < DZ; ++kk)
                    s = fmaf(Gk[kk * DZ + tid], muv[kk], s);
                mupr[tid] = s;
            }
            __syncthreads();
            // P_pr = F * U + Q   (At = G, B = U)
#pragma unroll
            for (int e = 0; e < 64; ++e) acc[e] = 0.f;
            mm_core<8, 8, DZ>(Gk, DZ, Ub, DZ, i08, j08, acc);
#pragma unroll
            for (int a = 0; a < 8; ++a) {
                float4 q0 = *reinterpret_cast<const float4*>(&Qk[(i08 + a) * DZ + j08]);
                float4 q1 = *reinterpret_cast<const float4*>(&Qk[(i08 + a) * DZ + j08 + 4]);
                acc[a * 8 + 0] += q0.x; acc[a * 8 + 1] += q0.y; acc[a * 8 + 2] += q0.z; acc[a * 8 + 3] += q0.w;
                acc[a * 8 + 4] += q1.x; acc[a * 8 + 5] += q1.y; acc[a * 8 + 6] += q1.z; acc[a * 8 + 7] += q1.w;
            }
#pragma unroll
            for (int a = 0; a < 8; ++a)
#pragma unroll
                for (int b = 0; b < 8; ++b)
                    Pl[(i08 + a) * DZ + (j08 + b)] = acc[a * 8 + b];
            __syncthreads();
        } else {
            if (tid < DZ) mupr[tid] = muv[tid];
            __syncthreads();
        }

        // ---------- measurement update ----------
        // CPt = P_pr * Ct (128x64); also CP = CPt^T (64x128)
        float a32[32];
#pragma unroll
        for (int e = 0; e < 32; ++e) a32[e] = 0.f;
        mm_core<8, 4, DZ>(Pl, DZ, Ct, DX, i08, j04, a32);
#pragma unroll
        for (int a = 0; a < 8; ++a)
#pragma unroll
            for (int b = 0; b < 4; ++b) {
                float v = a32[a * 4 + b];
                Ub[(i08 + a) * DX + (j04 + b)] = v;            // CPt at Ub[0:8192)
                Ub[8192 + (j04 + b) * DZ + (i08 + a)] = v;     // CP  at Ub[8192:16384)
            }
        __syncthreads();

        // S = C * CPt + R + jitter*I  (64x64) -> overwrites Ub[0:4096)
        float a16[16];
#pragma unroll
        for (int e = 0; e < 16; ++e) a16[e] = 0.f;
        mm_core<4, 4, DZ>(Ct, DX, Ub, DX, i04, j04, a16);
#pragma unroll
        for (int a = 0; a < 4; ++a)
#pragma unroll
            for (int b = 0; b < 4; ++b) {
                a16[a * 4 + b] += Rm[(i04 + a) * DX + (j04 + b)];
                if ((i04 + a) == (j04 + b)) a16[a * 4 + b] += JITTER_C;
            }
        __syncthreads();
#pragma unroll
        for (int a = 0; a < 4; ++a)
#pragma unroll
            for (int b = 0; b < 4; ++b)
                Ub[(i04 + a) * DX + (j04 + b)] = a16[a * 4 + b];
        __syncthreads();

        // y = x - C mu_pr
        if (tid < DX) {
            float s = xs[(size_t)k * DX + tid];
            for (int z = 0; z < DZ; ++z)
                s -= Cm[tid * DZ + z] * mupr[z];
            yv[tid] = s;
        }

        // ---------- Newton-Schulz S^{-1} (warm-started) ----------
        {
            float* Sp = Ub;
            float* Tp = Ub + 4096;
            float tacc[16];
#pragma unroll
            for (int e = 0; e < 16; ++e) tacc[e] = 0.f;
            mm_core<4, 4, DX>(Sp, DX, Xinv, DX, i04, j04, tacc);   // T = S*X
            if (tid == 0) red[0] = 0.f;
            __syncthreads();
            float pr = 0.f;
#pragma unroll
            for (int a = 0; a < 4; ++a)
#pragma unroll
                for (int b = 0; b < 4; ++b) {
                    float d = (((i04 + a) == (j04 + b)) ? 1.f : 0.f) - tacc[a * 4 + b];
                    pr += d * d;
                }
            atomicAdd(&red[0], pr);
#pragma unroll
            for (int a = 0; a < 4; ++a)
#pragma unroll
                for (int b = 0; b < 4; ++b)
                    Tp[(i04 + a) * DX + (j04 + b)] = tacc[a * 4 + b];
            __syncthreads();
            const bool cold = !(red[0] <= 0.04f);   // ||I-SX||_F^2 check (NaN -> cold)
            const int iters = cold ? 16 : 3;
            if (cold) {
                if (tid < DX) {
                    float s = 0.f;
                    for (int j = 0; j < DX; ++j) s += fabsf(Sp[tid * DX + j]);
                    rowsum[tid] = s;
                }
                __syncthreads();
                if (tid == 0) {
                    float mx = 0.f;
                    for (int m = 0; m < DX; ++m) mx = fmaxf(mx, rowsum[m]);
                    red[0] = 1.f / mx;
                }
                __syncthreads();
                float inv = red[0];
#pragma unroll
                for (int a = 0; a < 4; ++a)
#pragma unroll
                    for (int b = 0; b < 4; ++b)
                        Xinv[(i04 + a) * DX + (j04 + b)] = ((i04 + a) == (j04 + b)) ? inv : 0.f;
                __syncthreads();
#pragma unroll
                for (int e = 0; e < 16; ++e) tacc[e] = 0.f;
                mm_core<4, 4, DX>(Sp, DX, Xinv, DX, i04, j04, tacc);
#pragma unroll
                for (int a = 0; a < 4; ++a)
#pragma unroll
                    for (int b = 0; b < 4; ++b)
                        Tp[(i04 + a) * DX + (j04 + b)] = tacc[a * 4 + b];
                __syncthreads();
            }
            for (int it = 0; it < iters; ++it) {
                float xa[16];
#pragma unroll
                for (int e = 0; e < 16; ++e) xa[e] = 0.f;
                mm_core<4, 4, DX>(Xinv, DX, Tp, DX, i04, j04, xa);  // X*T
                float xn[16];
#pragma unroll
                for (int a = 0; a < 4; ++a)
#pragma unroll
                    for (int b = 0; b < 4; ++b)
                        xn[a * 4 + b] = 2.f * Xinv[(i04 + a) * DX + (j04 + b)] - xa[a * 4 + b];
                __syncthreads();
#pragma unroll
                for (int a = 0; a < 4; ++a)
#pragma unroll
                    for (int b = 0; b < 4; ++b)
                        Xinv[(i04 + a) * DX + (j04 + b)] = xn[a * 4 + b];
                __syncthreads();
                if (it + 1 < iters) {
                    float ta[16];
#pragma unroll
                    for (int e = 0; e < 16; ++e) ta[e] = 0.f;
                    mm_core<4, 4, DX>(Sp, DX, Xinv, DX, i04, j04, ta);
#pragma unroll
                    for (int a = 0; a < 4; ++a)
#pragma unroll
                        for (int b = 0; b < 4; ++b)
                            Tp[(i04 + a) * DX + (j04 + b)] = ta[a * 4 + b];
                    __syncthreads();
                }
            }
            // symmetrize X
            float xsym[16];
#pragma unroll
            for (int a = 0; a < 4; ++a)
#pragma unroll
                for (int b = 0; b < 4; ++b)
                    xsym[a * 4 + b] = 0.5f * (Xinv[(i04 + a) * DX + (j04 + b)] +
                                              Xinv[(j04 + b) * DX + (i04 + a)]);
            __syncthreads();
#pragma unroll
            for (int a = 0; a < 4; ++a)
#pragma unroll
                for (int b = 0; b < 4; ++b)
                    Xinv[(i04 + a) * DX + (j04 + b)] = xsym[a * 4 + b];
            __syncthreads();
        }

        // Kgt = Sinv * CP  (64x128) -> Ub[0:8192)
        float kg[32];
#pragma unroll
        for (int e = 0; e < 32; ++e) kg[e] = 0.f;
        mm_core<4, 8, DX>(Xinv, DX, Ub + 8192, DZ, i04, j08, kg);
#pragma unroll
        for (int a = 0; a < 4; ++a)
#pragma unroll
            for (int b = 0; b < 8; ++b)
                Ub[(i04 + a) * DZ + (j08 + b)] = kg[a * 8 + b];
        __syncthreads();

        // mu_u = mu_pr + Kg y
        if (tid < DZ) {
            float s = mupr[tid];
            for (int m = 0; m < DX; ++m)
                s = fmaf(Ub[m * DZ + tid], yv[m], s);
            muv[tid] = s;
            mu_out[(size_t)k * DZ + tid] = s;
        }

        // P_u = P_pr - Kg * CP ; symmetrize ; store
        float pa[64];
#pragma unroll
        for (int e = 0; e < 64; ++e) pa[e] = 0.f;
        mm_core<8, 8, DX>(Ub, DZ, Ub + 8192, DZ, i08, j08, pa);
#pragma unroll
        for (int a = 0; a < 8; ++a)
#pragma unroll
            for (int b = 0; b < 8; ++b)
                pa[a * 8 + b] = Pl[(i08 + a) * DZ + (j08 + b)] - pa[a * 8 + b];
#pragma unroll
        for (int a = 0; a < 8; ++a)
#pragma unroll
            for (int b = 0; b < 8; ++b)
                Pl[(i08 + a) * DZ + (j08 + b)] = pa[a * 8 + b];
        __syncthreads();
#pragma unroll
        for (int a = 0; a < 8; ++a)
#pragma unroll
            for (int b = 0; b < 8; ++b)
                pa[a * 8 + b] = 0.5f * (pa[a * 8 + b] + Pl[(j08 + b) * DZ + (i08 + a)]);
        __syncthreads();
        {
            float* po = P_out + (size_t)k * (DZ * DZ);
#pragma unroll
            for (int a = 0; a < 8; ++a)
#pragma unroll
                for (int b = 0; b < 8; ++b)
                    Pl[(i08 + a) * DZ + (j08 + b)] = pa[a * 8 + b];
#pragma unroll
            for (int a = 0; a < 8; ++a) {
                float4 v0 = make_float4(pa[a * 8 + 0], pa[a * 8 + 1], pa[a * 8 + 2], pa[a * 8 + 3]);
                float4 v1 = make_float4(pa[a * 8 + 4], pa[a * 8 + 5], pa[a * 8 + 6], pa[a * 8 + 7]);
                *reinterpret_cast<float4*>(&po[(i08 + a) * DZ + j08]) = v0;
                *reinterpret_cast<float4*>(&po[(i08 + a) * DZ + j08 + 4]) = v1;
            }
        }
        __syncthreads();
    }

    // persist state for next chunk
    for (int i = tid; i < DZ * DZ; i += 256) state[i] = Pl[i];
    if (tid < DZ) state[16384 + tid] = muv[tid];
    for (int i = tid; i < DX * DX; i += 256) state[16512 + i] = Xinv[i];
}

// =====================================================================
// host: gamma coefficients of the RK stability polynomial R(z)=sum g_m z^m
// =====================================================================
static void compute_gamma(double g[7])
{
    const double A[6][5] = {
        {0, 0, 0, 0, 0},
        {0.161, 0, 0, 0, 0},
        {-0.008480655492356989, 0.335480655492357, 0, 0, 0},
        {2.8971530571054935, -6.359448489975075, 4.3622954328695815, 0, 0},
        {5.325864828439257, -11.748883564062828, 7.4955393428898365, -0.09249506636175525, 0},
        {5.86145544294642, -12.92096931784711, 8.159367898576159, -0.071584973281401, -0.028269050394068383}};
    const double B[6] = {0.09646076681806523, 0.01, 0.4798896504144996,
                         1.379008574103742, -3.290069515436081, 2.324710524099774};
    double e[6][6];
    for (int i = 0; i < 6; ++i)
        for (int d = 0; d < 6; ++d) e[i][d] = 0.0;
    for (int i = 0; i < 6; ++i) {
        e[i][0] = 1.0;
        for (int j = 0; j < i; ++j)
            for (int d = 0; d < 5; ++d)
                e[i][d + 1] += A[i][j] * e[j][d];
    }
    g[0] = 1.0;
    for (int m = 1; m <= 6; ++m) {
        double s = 0.0;
        for (int i = 0; i < 6; ++i) s += B[i] * e[i][m - 1];
        g[m] = s;
    }
}

extern "C" void kernel_launch(void* const* d_in, const int* in_sizes, int n_in,
                              void* d_out, int out_size, void* d_ws, size_t ws_size,
                              hipStream_t stream)
{
    const float* xs  = (const float*)d_in[0];
    const float* ts  = (const float*)d_in[1];
    const float* es  = (const float*)d_in[2];
    const float* mu0 = (const float*)d_in[3];
    const float* P0  = (const float*)d_in[4];
    const float* A_s = (const float*)d_in[5];
    const float* b_s = (const float*)d_in[6];
    const float* Qch = (const float*)d_in[7];
    const float* Cm  = (const float*)d_in[8];
    const float* Rm  = (const float*)d_in[9];
    const int T = in_sizes[1];

    float* mu_out = (float*)d_out;
    float* P_out  = mu_out + (size_t)T * DZ;

    float* ws = (float*)d_ws;
    float* Ct    = ws;                 // 8192 floats
    float* state = ws + 8192;          // 20608 floats (P,mu,Sinv)
    float* chunkbase = ws + 28800;
    const long ws_floats = (long)(ws_size / 4);
    long avail = ws_floats - 28800;
    if (avail < 0) avail = 0;
    int mspc = (int)(avail / (2 * DZ * DZ + DZ));
    if (mspc < 1) mspc = 1;
    if (mspc > T - 1 && T > 1) mspc = T - 1;

    double g[7];
    compute_gamma(g);
    const float g1 = (float)g[1], g2 = (float)g[2], g3 = (float)g[3];
    const float g4 = (float)g[4], g5 = (float)g[5], g6 = (float)g[6];

    hipLaunchKernelGGL(kf_prep, dim3(1), dim3(256), 0, stream, Cm, Ct);

    if (T <= 1) {
        hipLaunchKernelGGL(kf_phase2, dim3(1), dim3(256), 0, stream,
                           xs, chunkbase, chunkbase, chunkbase, Ct, Cm, Rm, mu0, P0,
                           mu_out, P_out, state, 0, T, 1);
        return;
    }

    float* Gb = chunkbase;
    float* Qb = Gb + (size_t)mspc * (DZ * DZ);
    float* cb = Qb + (size_t)mspc * (DZ * DZ);

    int done = 0;
    bool first = true;
    while (done < T - 1) {
        int cs = T - 1 - done;
        if (cs > mspc) cs = mspc;
        const int pred_start = done + 1;
        hipLaunchKernelGGL(kf_phase1, dim3(cs), dim3(256), 0, stream,
                           A_s, b_s, Qch, es, ts, Gb, Qb, cb, pred_start,
                           g1, g2, g3, g4, g5, g6);
        const int k0 = first ? 0 : pred_start;
        const int k1 = pred_start + cs;
        hipLaunchKernelGGL(kf_phase2, dim3(1), dim3(256), 0, stream,
                           xs, Gb, Qb, cb, Ct, Cm, Rm, mu0, P0,
                           mu_out, P_out, state, k0, k1, pred_start);
        done += cs;
        first = false;
    }
}